// Round 4
// baseline (241.762 us; speedup 1.0000x reference)
//
#include <hip/hip_runtime.h>
#include <math.h>

#define BB 4
#define CC 32
#define HWSZ (512*512)
#define NMAX 128              // max instances supported (actual N=100 at runtime)
#define NP 132                // padded LDS stride for [c][n]
#define SS (NMAX * CC)        // 4096: fixed stride for per-block / per-batch arrays

#define PPB_S 2048            // pixels per block, k_seg_sum
#define CH_S (HWSZ / PPB_S)   // 128 chunks per batch
#define NBLK_S (BB * CH_S)    // 512 blocks

#define PPB_V 1024            // pixels per block, k_var
#define CH_V (HWSZ / PPB_V)   // 256 chunks per batch
#define NBLK_V (BB * CH_V)    // 1024 blocks

#define DSLICE 8              // dist-term slice blocks per batch (inside k_var)

#define DELTA_VAR_C 0.75f
#define DELTA_DIST_C 2.0f
#define GAMMA_C 0.001f
#define FXS 1048576.0f        // fixed-point scale 2^20
#define FXI (1.0f / 1048576.0f)

#define LD4(p) (*(const float4*)(p))

// block reduce over 256 threads (4 waves of 64); result valid on tid==0
__device__ __forceinline__ float block_reduce_256(float v, float* red, int tid) {
    #pragma unroll
    for (int o = 32; o > 0; o >>= 1) v += __shfl_down(v, o, 64);
    if ((tid & 63) == 0) red[tid >> 6] = v;
    __syncthreads();
    if (tid == 0) v = red[0] + red[1] + red[2] + red[3];
    return v;
}

// ---- Kernel 1: per-(batch,instance) partial sums + counts, NO global atomics --
__global__ __launch_bounds__(256) void k_seg_sum(
    const float* __restrict__ in, const int* __restrict__ lbl,
    const int* __restrict__ n_ptr, int* __restrict__ part_sums,
    unsigned int* __restrict__ part_cnts)
{
    const int N = *n_ptr;
    __shared__ int s_sum[CC * NP];
    __shared__ unsigned int s_cnt[NMAX];
    const int tid = threadIdx.x;

    for (int i = tid; i < CC * NP; i += 256) s_sum[i] = 0;
    for (int i = tid; i < NMAX; i += 256) s_cnt[i] = 0u;
    __syncthreads();

    const int b = blockIdx.x / CH_S;
    const int p0 = (blockIdx.x % CH_S) * PPB_S;

    const int* lb = lbl + (size_t)b * HWSZ + p0 + tid * 8;
    int4 l4a = *(const int4*)(lb);
    int4 l4b = *(const int4*)(lb + 4);
    int lab[8] = {l4a.x, l4a.y, l4a.z, l4a.w, l4b.x, l4b.y, l4b.z, l4b.w};

    #pragma unroll
    for (int i = 0; i < 8; i++) atomicAdd(&s_cnt[lab[i]], 1u);

    const float* p = in + (size_t)b * CC * HWSZ + p0 + (size_t)tid * 8;

    // 4 channels in flight (8 float4 loads / lane)
    float4 buf[4][2];
    #pragma unroll
    for (int k = 0; k < 4; k++) {
        const float* q = p + (size_t)k * HWSZ;
        buf[k][0] = LD4(q); buf[k][1] = LD4(q + 4);
    }
    for (int c0 = 0; c0 < CC; c0 += 4) {
        float4 cur[4][2];
        #pragma unroll
        for (int k = 0; k < 4; k++) { cur[k][0] = buf[k][0]; cur[k][1] = buf[k][1]; }
        if (c0 + 4 < CC) {
            #pragma unroll
            for (int k = 0; k < 4; k++) {
                const float* q = p + (size_t)(c0 + 4 + k) * HWSZ;
                buf[k][0] = LD4(q); buf[k][1] = LD4(q + 4);
            }
        }
        #pragma unroll
        for (int k = 0; k < 4; k++) {
            float v[8] = {cur[k][0].x, cur[k][0].y, cur[k][0].z, cur[k][0].w,
                          cur[k][1].x, cur[k][1].y, cur[k][1].z, cur[k][1].w};
            const int base = (c0 + k) * NP;
            #pragma unroll
            for (int i = 0; i < 8; i++)
                atomicAdd(&s_sum[base + lab[i]], (int)rintf(v[i] * FXS));
        }
    }
    __syncthreads();

    // coalesced, non-atomic partial flush
    int* my_sum = part_sums + (size_t)blockIdx.x * SS;
    for (int i = tid; i < N * CC; i += 256)
        my_sum[i] = s_sum[(i % CC) * NP + (i / CC)];
    unsigned int* my_cnt = part_cnts + (size_t)blockIdx.x * NMAX;
    for (int i = tid; i < N; i += 256)
        my_cnt[i] = s_cnt[i];
}

// ---- Kernel 2: tree-reduce partials -> means (float) + invc ----
// grid: BB * 16 blocks; block covers 256 outputs of one batch
__global__ __launch_bounds__(256) void k_reduce(
    const int* __restrict__ part_sums, const unsigned int* __restrict__ part_cnts,
    const int* __restrict__ n_ptr, float* __restrict__ means,
    float* __restrict__ invc)
{
    const int N = *n_ptr;
    const int b = blockIdx.x >> 4;
    const int i = (blockIdx.x & 15) * 256 + threadIdx.x;
    if (i >= N * CC) return;
    const int n = i / CC;

    long long s = 0;
    unsigned int cnt = 0;
    const int* ps = part_sums + (size_t)b * CH_S * SS + i;
    const unsigned int* pc = part_cnts + (size_t)b * CH_S * NMAX + n;
    #pragma unroll 4
    for (int k = 0; k < CH_S; k++) {
        s += ps[(size_t)k * SS];
        cnt += pc[(size_t)k * NMAX];
    }
    float mu = (float)s * FXI / (float)cnt;
    means[(size_t)b * SS + i] = mu;
    if ((i & (CC - 1)) == 0) invc[b * NMAX + n] = 1.0f / (float)cnt;
}

// ---- Kernel 3: variance (hinge) term; dist+reg folded into first slice blocks --
__global__ __launch_bounds__(256) void k_var(
    const float* __restrict__ in, const int* __restrict__ lbl,
    const int* __restrict__ n_ptr, const float* __restrict__ means,
    const float* __restrict__ invc_g, int* __restrict__ out_acc)
{
    const int N = *n_ptr;
    __shared__ float m_t[CC * NP];   // [c][n] transposed
    __shared__ float s_invc[NMAX];
    __shared__ float red[4];
    const int tid = threadIdx.x;

    const int b = blockIdx.x / CH_V;
    const int chunk = blockIdx.x % CH_V;
    const int p0 = chunk * PPB_V;

    for (int i = tid; i < N * CC; i += 256)
        m_t[(i % CC) * NP + (i / CC)] = means[(size_t)b * SS + i];
    for (int i = tid; i < N; i += 256)
        s_invc[i] = invc_g[b * NMAX + i];
    __syncthreads();

    const int* lb = lbl + (size_t)b * HWSZ + p0 + tid * 4;
    int4 l4 = *(const int4*)(lb);
    int lab[4] = {l4.x, l4.y, l4.z, l4.w};
    float acc[4] = {0.f, 0.f, 0.f, 0.f};

    const float* p = in + (size_t)b * CC * HWSZ + p0 + (size_t)tid * 4;

    // 4 channels in flight
    float4 buf[4];
    #pragma unroll
    for (int k = 0; k < 4; k++) buf[k] = LD4(p + (size_t)k * HWSZ);
    for (int c0 = 0; c0 < CC; c0 += 4) {
        float4 cur[4];
        #pragma unroll
        for (int k = 0; k < 4; k++) cur[k] = buf[k];
        if (c0 + 4 < CC) {
            #pragma unroll
            for (int k = 0; k < 4; k++) buf[k] = LD4(p + (size_t)(c0 + 4 + k) * HWSZ);
        }
        #pragma unroll
        for (int k = 0; k < 4; k++) {
            float v[4] = {cur[k].x, cur[k].y, cur[k].z, cur[k].w};
            const int base = (c0 + k) * NP;
            #pragma unroll
            for (int i = 0; i < 4; i++) {
                float d = v[i] - m_t[base + lab[i]];
                acc[i] += d * d;
            }
        }
    }

    float vsum = 0.f;
    #pragma unroll
    for (int i = 0; i < 4; i++) {
        float nm = sqrtf(acc[i]);
        float t = fmaxf(nm - DELTA_VAR_C, 0.f);
        vsum += t * t * s_invc[lab[i]];
    }
    float total = vsum * (1.0f / ((float)N * (float)BB));

    // fold pairwise-distance + regularization terms into first DSLICE blocks/batch
    if (chunk < DSLICE) {
        float dist_sum = 0.f;
        for (int pr = chunk * 256 + tid; pr < N * N; pr += DSLICE * 256) {
            int i = pr / N, j = pr - i * N;
            if (i == j) continue;
            float d2 = 0.f;
            #pragma unroll
            for (int c = 0; c < CC; c++) {
                float d = m_t[c * NP + i] - m_t[c * NP + j];
                d2 += d * d;
            }
            float dm = (d2 > 0.f) ? sqrtf(d2) : 1.0f;   // match jnp.where(d2>0,d2,1)
            float h = fmaxf(2.0f * DELTA_DIST_C - dm, 0.f);
            dist_sum += h * h;
        }
        total += dist_sum * (1.0f / ((float)N * (float)(N - 1) * (float)BB));
        if (chunk == 0) {
            float reg_sum = 0.f;
            for (int n = tid; n < N; n += 256) {
                float s = 0.f;
                #pragma unroll
                for (int c = 0; c < CC; c++) { float v = m_t[c * NP + n]; s += v * v; }
                reg_sum += sqrtf(s);
            }
            total += reg_sum * (GAMMA_C / ((float)N * (float)BB));
        }
    }

    float tot = block_reduce_256(total, red, tid);
    if (tid == 0)
        atomicAdd(out_acc, (int)rintf(tot * FXS));
}

// ---- Kernel 4: fixed-point -> float output ----
__global__ void k_final(const int* __restrict__ out_acc, float* __restrict__ out) {
    if (threadIdx.x == 0 && blockIdx.x == 0)
        *out = (float)(*out_acc) * FXI;
}

extern "C" void kernel_launch(void* const* d_in, const int* in_sizes, int n_in,
                              void* d_out, int out_size, void* d_ws, size_t ws_size,
                              hipStream_t stream) {
    (void)in_sizes; (void)n_in; (void)out_size; (void)ws_size;
    const float* in  = (const float*)d_in[0];
    const int*   lbl = (const int*)d_in[1];
    const int*   n_ptr = (const int*)d_in[2];
    float* out = (float*)d_out;

    int* part_sums = (int*)d_ws;                                   // NBLK_S * SS
    unsigned int* part_cnts = (unsigned int*)(part_sums + (size_t)NBLK_S * SS); // NBLK_S*NMAX
    float* means = (float*)(part_cnts + (size_t)NBLK_S * NMAX);    // BB * SS
    float* invc  = means + (size_t)BB * SS;                        // BB * NMAX
    int* out_acc = (int*)(invc + (size_t)BB * NMAX);               // 1

    hipMemsetAsync(out_acc, 0, sizeof(int), stream);

    k_seg_sum<<<NBLK_S, 256, 0, stream>>>(in, lbl, n_ptr, part_sums, part_cnts);
    k_reduce<<<BB * 16, 256, 0, stream>>>(part_sums, part_cnts, n_ptr, means, invc);
    k_var<<<NBLK_V, 256, 0, stream>>>(in, lbl, n_ptr, means, invc, out_acc);
    k_final<<<1, 64, 0, stream>>>(out_acc, out);
}

// Round 5
// 225.253 us; speedup vs baseline: 1.0733x; 1.0733x over previous
//
#include <hip/hip_runtime.h>
#include <math.h>

#define BB 4
#define CC 32
#define HWSZ (512*512)
#define NMAX 128              // max instances supported (actual N=100 at runtime)
#define NP 132                // padded LDS stride (>= NMAX) for [c][n] float arrays
#define NP64 133              // padded LDS stride (>= NMAX) for u64 pair-sums
#define SS (NMAX * CC)        // 4096: per-batch stride for sums/means

#define PPB 2048              // pixels per block (both big kernels)
#define CHUNKS (HWSZ / PPB)   // 128 chunks per batch
#define NBLK (BB * CHUNKS)    // 512 blocks

#define DSLICE 8              // dist-term slice blocks per batch (inside k_var)

#define DELTA_VAR_C 0.75f
#define DELTA_DIST_C 2.0f
#define GAMMA_C 0.001f
#define FXS 1048576.0f        // fixed-point scale 2^20
#define FXI (1.0f / 1048576.0f)
#define BIAS 16777216         // 2^24: per-add bias keeping u64 halves non-negative

#define LD4(p) (*(const float4*)(p))

// block reduce over 256 threads (4 waves of 64); result valid on tid==0
__device__ __forceinline__ float block_reduce_256(float v, float* red, int tid) {
    #pragma unroll
    for (int o = 32; o > 0; o >>= 1) v += __shfl_down(v, o, 64);
    if ((tid & 63) == 0) red[tid >> 6] = v;
    __syncthreads();
    if (tid == 0) v = red[0] + red[1] + red[2] + red[3];
    return v;
}

// ---- Kernel 1: per-(batch,instance) sums + counts; packed u64 LDS atomics ----
__global__ __launch_bounds__(256) void k_seg_sum(
    const float* __restrict__ in, const int* __restrict__ lbl,
    const int* __restrict__ n_ptr, int* __restrict__ sums_i,
    unsigned int* __restrict__ counts_u)
{
    const int N = *n_ptr;
    __shared__ unsigned long long s_sum[(CC / 2) * NP64];  // [c/2][n], lo=c, hi=c+1
    __shared__ unsigned int s_cnt[NMAX];
    const int tid = threadIdx.x;

    for (int i = tid; i < (CC / 2) * NP64; i += 256) s_sum[i] = 0ull;
    for (int i = tid; i < NMAX; i += 256) s_cnt[i] = 0u;
    __syncthreads();

    const int b = blockIdx.x / CHUNKS;
    const int p0 = (blockIdx.x % CHUNKS) * PPB;

    const int* lb = lbl + (size_t)b * HWSZ + p0 + tid * 8;
    int4 l4a = *(const int4*)(lb);
    int4 l4b = *(const int4*)(lb + 4);
    int lab[8] = {l4a.x, l4a.y, l4a.z, l4a.w, l4b.x, l4b.y, l4b.z, l4b.w};

    #pragma unroll
    for (int i = 0; i < 8; i++) atomicAdd(&s_cnt[lab[i]], 1u);

    const float* p = in + (size_t)b * CC * HWSZ + p0 + (size_t)tid * 8;

    // channel pair (c, c+1) per iteration; 4 float4 loads in flight
    float4 a0 = LD4(p);            float4 b0 = LD4(p + 4);
    float4 a1 = LD4(p + HWSZ);     float4 b1 = LD4(p + HWSZ + 4);

    for (int c = 0; c < CC; c += 2) {
        float4 ca0 = a0, cb0 = b0, ca1 = a1, cb1 = b1;
        if (c + 2 < CC) {
            const float* q = p + (size_t)(c + 2) * HWSZ;
            a0 = LD4(q);          b0 = LD4(q + 4);
            a1 = LD4(q + HWSZ);   b1 = LD4(q + HWSZ + 4);
        }
        float v0[8] = {ca0.x, ca0.y, ca0.z, ca0.w, cb0.x, cb0.y, cb0.z, cb0.w};
        float v1[8] = {ca1.x, ca1.y, ca1.z, ca1.w, cb1.x, cb1.y, cb1.z, cb1.w};
        unsigned long long* row = &s_sum[(c >> 1) * NP64];
        #pragma unroll
        for (int i = 0; i < 8; i++) {
            // truncating cvt (unbiased for symmetric data); bias keeps halves >= 0
            unsigned int lo = (unsigned int)((int)(v0[i] * FXS) + BIAS);
            unsigned int hi = (unsigned int)((int)(v1[i] * FXS) + BIAS);
            unsigned long long pk = (unsigned long long)lo |
                                    ((unsigned long long)hi << 32);
            atomicAdd(&row[lab[i]], pk);
        }
    }
    __syncthreads();

    // flush: unbias with per-label count, global int atomics (L2-pipelined)
    for (int i = tid; i < N * CC; i += 256) {
        int n = i / CC, c = i % CC;
        unsigned long long v = s_sum[(c >> 1) * NP64 + n];
        unsigned int half = (c & 1) ? (unsigned int)(v >> 32) : (unsigned int)v;
        long long val = (long long)half - ((long long)s_cnt[n] << 24);
        if (val != 0)
            atomicAdd(&sums_i[(size_t)b * SS + i], (int)val);
    }
    for (int i = tid; i < N; i += 256) {
        unsigned int cv = s_cnt[i];
        if (cv) atomicAdd(&counts_u[b * NMAX + i], cv);
    }
}

// ---- Kernel 2: means (from sums) + variance hinge + dist + reg, all fused ----
__global__ __launch_bounds__(256) void k_var(
    const float* __restrict__ in, const int* __restrict__ lbl,
    const int* __restrict__ n_ptr, const int* __restrict__ sums_i,
    const unsigned int* __restrict__ counts_u, int* __restrict__ out_acc)
{
    const int N = *n_ptr;
    __shared__ float m_t[CC * NP];   // [c][n] transposed means
    __shared__ float s_invc[NMAX];
    __shared__ float red[4];
    const int tid = threadIdx.x;

    const int b = blockIdx.x / CHUNKS;
    const int chunk = blockIdx.x % CHUNKS;
    const int p0 = chunk * PPB;

    for (int i = tid; i < N; i += 256)
        s_invc[i] = 1.0f / (float)counts_u[b * NMAX + i];
    __syncthreads();
    for (int i = tid; i < N * CC; i += 256) {
        int n = i / CC, c = i % CC;
        m_t[c * NP + n] = (float)sums_i[(size_t)b * SS + i] * FXI * s_invc[n];
    }
    __syncthreads();

    const int* lb = lbl + (size_t)b * HWSZ + p0 + tid * 8;
    int4 l4a = *(const int4*)(lb);
    int4 l4b = *(const int4*)(lb + 4);
    int lab[8] = {l4a.x, l4a.y, l4a.z, l4a.w, l4b.x, l4b.y, l4b.z, l4b.w};
    float acc[8] = {0.f, 0.f, 0.f, 0.f, 0.f, 0.f, 0.f, 0.f};

    const float* p = in + (size_t)b * CC * HWSZ + p0 + (size_t)tid * 8;
    float4 a0 = LD4(p);            float4 b0 = LD4(p + 4);
    float4 a1 = LD4(p + HWSZ);     float4 b1 = LD4(p + HWSZ + 4);

    for (int c = 0; c < CC; c += 2) {
        float4 ca0 = a0, cb0 = b0, ca1 = a1, cb1 = b1;
        if (c + 2 < CC) {
            const float* q = p + (size_t)(c + 2) * HWSZ;
            a0 = LD4(q);          b0 = LD4(q + 4);
            a1 = LD4(q + HWSZ);   b1 = LD4(q + HWSZ + 4);
        }
        float v0[8] = {ca0.x, ca0.y, ca0.z, ca0.w, cb0.x, cb0.y, cb0.z, cb0.w};
        #pragma unroll
        for (int i = 0; i < 8; i++) {
            float d = v0[i] - m_t[c * NP + lab[i]];
            acc[i] += d * d;
        }
        float v1[8] = {ca1.x, ca1.y, ca1.z, ca1.w, cb1.x, cb1.y, cb1.z, cb1.w};
        #pragma unroll
        for (int i = 0; i < 8; i++) {
            float d = v1[i] - m_t[(c + 1) * NP + lab[i]];
            acc[i] += d * d;
        }
    }

    float vsum = 0.f;
    #pragma unroll
    for (int i = 0; i < 8; i++) {
        float nm = sqrtf(acc[i]);
        float t = fmaxf(nm - DELTA_VAR_C, 0.f);
        vsum += t * t * s_invc[lab[i]];
    }
    float total = vsum * (1.0f / ((float)N * (float)BB));

    // fold pairwise-distance + regularization terms into first DSLICE blocks/batch
    if (chunk < DSLICE) {
        float dist_sum = 0.f;
        for (int pr = chunk * 256 + tid; pr < N * N; pr += DSLICE * 256) {
            int i = pr / N, j = pr - i * N;
            if (i == j) continue;
            float d2 = 0.f;
            #pragma unroll
            for (int c = 0; c < CC; c++) {
                float d = m_t[c * NP + i] - m_t[c * NP + j];
                d2 += d * d;
            }
            float dm = (d2 > 0.f) ? sqrtf(d2) : 1.0f;   // match jnp.where(d2>0,d2,1)
            float h = fmaxf(2.0f * DELTA_DIST_C - dm, 0.f);
            dist_sum += h * h;
        }
        total += dist_sum * (1.0f / ((float)N * (float)(N - 1) * (float)BB));
        if (chunk == 0) {
            float reg_sum = 0.f;
            for (int n = tid; n < N; n += 256) {
                float s = 0.f;
                #pragma unroll
                for (int c = 0; c < CC; c++) { float v = m_t[c * NP + n]; s += v * v; }
                reg_sum += sqrtf(s);
            }
            total += reg_sum * (GAMMA_C / ((float)N * (float)BB));
        }
    }

    float tot = block_reduce_256(total, red, tid);
    if (tid == 0)
        atomicAdd(out_acc, (int)rintf(tot * FXS));
}

// ---- Kernel 3: fixed-point -> float output ----
__global__ void k_final(const int* __restrict__ out_acc, float* __restrict__ out) {
    if (threadIdx.x == 0 && blockIdx.x == 0)
        *out = (float)(*out_acc) * FXI;
}

extern "C" void kernel_launch(void* const* d_in, const int* in_sizes, int n_in,
                              void* d_out, int out_size, void* d_ws, size_t ws_size,
                              hipStream_t stream) {
    (void)in_sizes; (void)n_in; (void)out_size; (void)ws_size;
    const float* in  = (const float*)d_in[0];
    const int*   lbl = (const int*)d_in[1];
    const int*   n_ptr = (const int*)d_in[2];
    float* out = (float*)d_out;

    int* sums_i = (int*)d_ws;                                          // BB*SS
    unsigned int* counts_u = (unsigned int*)(sums_i + BB * SS);        // BB*NMAX
    int* out_acc = (int*)(counts_u + BB * NMAX);                       // 1

    hipMemsetAsync(d_ws, 0, (size_t)(BB * SS + BB * NMAX + 1) * sizeof(int), stream);

    k_seg_sum<<<NBLK, 256, 0, stream>>>(in, lbl, n_ptr, sums_i, counts_u);
    k_var<<<NBLK, 256, 0, stream>>>(in, lbl, n_ptr, sums_i, counts_u, out_acc);
    k_final<<<1, 64, 0, stream>>>(out_acc, out);
}